// Round 8
// baseline (275.218 us; speedup 1.0000x reference)
//
#include <hip/hip_runtime.h>
#include <hip/hip_bf16.h>
#include <math.h>

// Problem constants (B,T,D,H) = (2,2048,1024,16), hd=64
#define B_  2
#define T_  2048
#define D_  1024
#define H_  16
#define HD_ 64

typedef __attribute__((ext_vector_type(8))) short bf16x8;
typedef __attribute__((ext_vector_type(4))) float f32x4;

#define GAS __attribute__((address_space(1)))
#define LAS __attribute__((address_space(3)))

#define LOG2E 1.4426950408889634f

static __device__ __forceinline__ unsigned short f2bf(float f) {
    __hip_bfloat16 h = __float2bfloat16(f);
    return *reinterpret_cast<unsigned short*>(&h);
}

// ---------------------------------------------------------------------------
// Kernel 0: fp32 -> bf16 cast, 8 elements/thread, 16B stores
// ---------------------------------------------------------------------------
__global__ __launch_bounds__(256) void cast_bf16(const float* __restrict__ in,
                                                 __hip_bfloat16* __restrict__ out,
                                                 int n8) {
    int i = blockIdx.x * 256 + threadIdx.x;
    if (i >= n8) return;
    float4 a = ((const float4*)in)[(size_t)i * 2];
    float4 b = ((const float4*)in)[(size_t)i * 2 + 1];
    union { unsigned short u[8]; bf16x8 v; } r;
    r.u[0] = f2bf(a.x); r.u[1] = f2bf(a.y); r.u[2] = f2bf(a.z); r.u[3] = f2bf(a.w);
    r.u[4] = f2bf(b.x); r.u[5] = f2bf(b.y); r.u[6] = f2bf(b.z); r.u[7] = f2bf(b.w);
    *(bf16x8*)(out + (size_t)i * 8) = r.v;
}

// ---------------------------------------------------------------------------
// Kernel A: qk projection GEMM, bf16 MFMA (m97 structure).
//   q is pre-scaled by 0.125*log2e (softmax in exp2 domain).
// ---------------------------------------------------------------------------
__global__ __launch_bounds__(256) void qk_gemm_mfma(const __hip_bfloat16* __restrict__ Xb,
                                                    const __hip_bfloat16* __restrict__ Wb,
                                                    const float* __restrict__ bias,
                                                    __hip_bfloat16* __restrict__ qws,
                                                    __hip_bfloat16* __restrict__ kws) {
    __shared__ __hip_bfloat16 As[128 * 32];   // linear row-major [128][32], 8 KB
    __shared__ __hip_bfloat16 Bs[128 * 32];

    const int tid  = threadIdx.x;
    const int w    = tid >> 6, lane = tid & 63;
    const int l16  = lane & 15, g = lane >> 4;
    const int wr   = w >> 1, wc = w & 1;
    const int m0   = blockIdx.y * 128, n0 = blockIdx.x * 128;
    const int K    = D_;

    const int sr = lane >> 2;
    const int sk = (lane & 3) * 8;

    f32x4 acc[4][4] = {};

    for (int k0 = 0; k0 < K; k0 += 32) {
        __syncthreads();
        #pragma unroll
        for (int p = 0; p < 2; ++p) {
            int s = w + p * 4;
            int r = s * 16 + sr;
            __builtin_amdgcn_global_load_lds(
                (const GAS void*)(const void*)(Xb + (size_t)(m0 + r) * K + k0 + sk),
                (LAS void*)(void*)((char*)As + s * 1024), 16, 0, 0);
            __builtin_amdgcn_global_load_lds(
                (const GAS void*)(const void*)(Wb + (size_t)(n0 + r) * K + k0 + sk),
                (LAS void*)(void*)((char*)Bs + s * 1024), 16, 0, 0);
        }
        __syncthreads();

        bf16x8 af[4], bfr[4];
        #pragma unroll
        for (int mi = 0; mi < 4; ++mi)
            af[mi] = *(const bf16x8*)(As + (wr * 64 + mi * 16 + l16) * 32 + g * 8);
        #pragma unroll
        for (int ni = 0; ni < 4; ++ni)
            bfr[ni] = *(const bf16x8*)(Bs + (wc * 64 + ni * 16 + l16) * 32 + g * 8);
        #pragma unroll
        for (int mi = 0; mi < 4; ++mi)
            #pragma unroll
            for (int ni = 0; ni < 4; ++ni)
                acc[mi][ni] = __builtin_amdgcn_mfma_f32_16x16x32_bf16(
                                  af[mi], bfr[ni], acc[mi][ni], 0, 0, 0);
    }

    #pragma unroll
    for (int ni = 0; ni < 4; ++ni) {
        int n = n0 + wc * 64 + ni * 16 + l16;
        float bv = bias[n];
        bool isq = (n < D_);
        int nn = isq ? n : n - D_;
        int h = nn >> 6, d = nn & 63;
        float scale = isq ? (0.125f * LOG2E) : 1.0f;
        __hip_bfloat16* dst = isq ? qws : kws;
        #pragma unroll
        for (int mi = 0; mi < 4; ++mi) {
            #pragma unroll
            for (int j = 0; j < 4; ++j) {
                int m = m0 + wr * 64 + mi * 16 + g * 4 + j;
                int b = m >> 11, t = m & (T_ - 1);
                dst[(((size_t)b * H_ + h) * T_ + t) * HD_ + d] =
                    __float2bfloat16((acc[mi][ni][j] + bv) * scale);
            }
        }
    }
}

// ---------------------------------------------------------------------------
// Kernel B: v = einsum('btjd,ij->bitd'), emitted TRANSPOSED bf16 (B,H,HD,T)
// ---------------------------------------------------------------------------
__global__ __launch_bounds__(256) void head_mix_v(const float* __restrict__ xt,
                                                  const float* __restrict__ vf,
                                                  __hip_bfloat16* __restrict__ vt) {
    __shared__ float xl[2][1024];
    __shared__ float f[256];
    const int pair = blockIdx.x;             // 0..2047
    const int b = pair >> 10;
    const int t = (pair & 1023) * 2;
    const float* xr = xt + ((size_t)b * T_ + t) * D_;
    const int tid = threadIdx.x;
    #pragma unroll
    for (int i = tid; i < 1024; i += 256) {
        xl[0][i] = xr[i];
        xl[1][i] = xr[1024 + i];
    }
    f[tid] = vf[tid];
    __syncthreads();
    #pragma unroll
    for (int p = 0; p < 4; ++p) {
        int o = tid + p * 256;
        int i = o >> 6, d = o & 63;
        float a0 = 0.f, a1 = 0.f;
        #pragma unroll
        for (int j = 0; j < 16; ++j) {
            float fv = f[i * 16 + j];
            a0 += fv * xl[0][j * 64 + d];
            a1 += fv * xl[1][j * 64 + d];
        }
        unsigned pk = (unsigned)f2bf(a0) | ((unsigned)f2bf(a1) << 16);
        *(unsigned*)&vt[(((size_t)b * H_ + i) * HD_ + d) * T_ + t] = pk;
    }
}

// ---------------------------------------------------------------------------
// Kernel C: causal ALiBi flash attention, bf16 MFMA 16x16x32.
//   4096 single-wave blocks, ONE q-tile (16 rows) each; longest-first order.
//   Swapped QK^T (S^T = mfma(K,Q)); softmax in exp2 domain; K register
//   double-buffer; P^T roundtrip via per-block LDS.
// ---------------------------------------------------------------------------
__global__ __launch_bounds__(64) void attn_mfma(const __hip_bfloat16* __restrict__ qws,
                                                const __hip_bfloat16* __restrict__ kws,
                                                const __hip_bfloat16* __restrict__ vtws,
                                                float* __restrict__ yws) {
    __shared__ float Pl[16][68];             // P^T tile: [q][key], 4.25 KB

    const int lane = threadIdx.x;            // 0..63
    const int l16  = lane & 15;
    const int g    = lane >> 4;

    // XCD swizzle: 8 XCDs x 512 blocks; each XCD owns 4 heads (KV fits L2).
    // Within an XCD, j descends (longest blocks dispatched first).
    const int bid    = blockIdx.x;           // 0..4095
    const int linear = (bid & 7) * 512 + (bid >> 3);
    const int bh     = linear >> 7;          // b*H + h
    const int j      = 127 - (linear & 127); // q-row-tile, longest first
    const int b = bh >> 4, h = bh & 15;
    const float slope_l2 = exp2f(-0.5f * (float)(h + 1)) * LOG2E;

    const __hip_bfloat16* qb = qws  + (size_t)bh * (T_ * HD_);
    const __hip_bfloat16* kb = kws  + (size_t)bh * (T_ * HD_);
    const __hip_bfloat16* vb = vtws + (size_t)bh * (HD_ * T_);

    const int tq0  = j * 16;
    const int q_hi = tq0 + 15;
    const int tq   = tq0 + l16;              // this lane's softmax row

    // Q fragments (B-operand of S^T, pre-scaled by 0.125*log2e):
    bf16x8 aq[2];
    #pragma unroll
    for (int ks = 0; ks < 2; ++ks)
        aq[ks] = *(const bf16x8*)(qb + (size_t)(tq0 + l16) * HD_ + ks * 32 + g * 8);

    f32x4 oacc[4] = {};                      // df -> Y[q=g*4+r][d=16df+l16]
    float m_s = -INFINITY, l_s = 0.f;

    bf16x8 kA[4][2], kB[4][2];

    auto loadK = [&](bf16x8 (&dst)[4][2], int k0) {
        #pragma unroll
        for (int kf = 0; kf < 4; ++kf)
            #pragma unroll
            for (int ks = 0; ks < 2; ++ks)
                dst[kf][ks] = *(const bf16x8*)(kb + (size_t)(k0 + kf * 16 + l16) * HD_ + ks * 32 + g * 8);
    };

    auto tile = [&](const bf16x8 (&bk)[4][2], int k0) {
        // V fragments for this tile (latency hidden under QK + softmax)
        bf16x8 bv[4][2];
        #pragma unroll
        for (int df = 0; df < 4; ++df)
            #pragma unroll
            for (int ks = 0; ks < 2; ++ks)
                bv[df][ks] = *(const bf16x8*)(vb + (size_t)(df * 16 + l16) * T_ + k0 + ks * 32 + g * 8);

        // S^T = K.Q : frag kf -> S^T[key=k0+kf*16+g*4+r][q=tq0+l16]
        f32x4 s[4] = {};
        #pragma unroll
        for (int kf = 0; kf < 4; ++kf)
            #pragma unroll
            for (int ks = 0; ks < 2; ++ks)
                s[kf] = __builtin_amdgcn_mfma_f32_16x16x32_bf16(bk[kf][ks], aq[ks], s[kf], 0, 0, 0);

        // bias + mask (exp2 domain); lane-local max, 2-hop reduce
        float pvv[4][4];
        float mx = -INFINITY;
        #pragma unroll
        for (int kf = 0; kf < 4; ++kf)
            #pragma unroll
            for (int r = 0; r < 4; ++r) {
                int kg = k0 + kf * 16 + g * 4 + r;
                float x = s[kf][r] + slope_l2 * (float)(kg - tq);
                x = (kg <= tq) ? x : -INFINITY;
                pvv[kf][r] = x;
                mx = fmaxf(mx, x);
            }
        mx = fmaxf(mx, __shfl_xor(mx, 16));
        mx = fmaxf(mx, __shfl_xor(mx, 32));
        float mnew = fmaxf(m_s, mx);
        float corr = exp2f(m_s - mnew);      // 0 on first tile
        m_s = mnew;
        float ps = 0.f;
        #pragma unroll
        for (int kf = 0; kf < 4; ++kf)
            #pragma unroll
            for (int r = 0; r < 4; ++r) {
                float p = exp2f(pvv[kf][r] - mnew);
                pvv[kf][r] = p;
                ps += p;
            }
        ps += __shfl_xor(ps, 16);
        ps += __shfl_xor(ps, 32);
        l_s = l_s * corr + ps;

        // P^T -> LDS [q][key], vector writes
        #pragma unroll
        for (int kf = 0; kf < 4; ++kf) {
            float4 w4 = make_float4(pvv[kf][0], pvv[kf][1], pvv[kf][2], pvv[kf][3]);
            *(float4*)&Pl[l16][kf * 16 + g * 4] = w4;
        }

        // rescale O (corr lives on softmax row q=l16; fetch per acc row)
        #pragma unroll
        for (int r = 0; r < 4; ++r) {
            float cr = __shfl(corr, g * 4 + r);
            #pragma unroll
            for (int df = 0; df < 4; ++df)
                oacc[df][r] *= cr;
        }

        // re-fragment P: A[m=q][k=key]; lane reads Pl[l16][ks*32+g*8..+7]
        bf16x8 ap[2];
        #pragma unroll
        for (int ks = 0; ks < 2; ++ks) {
            const float* pr = &Pl[l16][ks * 32 + g * 8];
            bf16x8 tmp;
            #pragma unroll
            for (int jj = 0; jj < 8; ++jj)
                tmp[jj] = (short)f2bf(pr[jj]);
            ap[ks] = tmp;
        }

        // Y += P.V
        #pragma unroll
        for (int df = 0; df < 4; ++df)
            #pragma unroll
            for (int ks = 0; ks < 2; ++ks)
                oacc[df] = __builtin_amdgcn_mfma_f32_16x16x32_bf16(ap[ks], bv[df][ks], oacc[df], 0, 0, 0);
    };

    // K-prefetched tile loop (register double buffer, static names)
    loadK(kA, 0);
    for (int k0 = 0; k0 <= q_hi; k0 += 128) {
        if (k0 + 64 <= q_hi) loadK(kB, k0 + 64);
        tile(kA, k0);
        if (k0 + 64 <= q_hi) {
            if (k0 + 128 <= q_hi) loadK(kA, k0 + 128);
            tile(kB, k0 + 64);
        }
    }

    // epilogue: y (B,T,H,HD) fp32
    #pragma unroll
    for (int r = 0; r < 4; ++r) {
        float lr  = __shfl(l_s, g * 4 + r);
        float inv = 1.0f / lr;
        int tqr = tq0 + g * 4 + r;
        #pragma unroll
        for (int df = 0; df < 4; ++df)
            yws[(((size_t)b * T_ + tqr) * H_ + h) * HD_ + df * 16 + l16] =
                oacc[df][r] * inv;
    }
}

// ---------------------------------------------------------------------------
// Kernel D: out = einsum('btjd,ij->btid', y, out_fact) -> (B,T,D) fp32
// ---------------------------------------------------------------------------
__global__ __launch_bounds__(256) void head_mix_out(const float* __restrict__ yws,
                                                    const float* __restrict__ of,
                                                    float* __restrict__ out) {
    __shared__ float yl[1024];
    __shared__ float f[256];
    const int row = blockIdx.x;
    const float* yr = yws + (size_t)row * D_;
    const int tid = threadIdx.x;
    #pragma unroll
    for (int i = tid; i < 1024; i += 256) yl[i] = yr[i];
    f[tid] = of[tid];
    __syncthreads();
    for (int o = tid; o < 1024; o += 256) {
        int i = o >> 6, d = o & 63;
        float acc = 0.f;
        #pragma unroll
        for (int j = 0; j < 16; ++j) acc += f[i * 16 + j] * yl[j * 64 + d];
        out[(size_t)row * D_ + o] = acc;
    }
}

// ---------------------------------------------------------------------------
extern "C" void kernel_launch(void* const* d_in, const int* in_sizes, int n_in,
                              void* d_out, int out_size, void* d_ws, size_t ws_size,
                              hipStream_t stream) {
    const float* x_norm   = (const float*)d_in[0];
    const float* xt       = (const float*)d_in[1];
    const float* qk_w     = (const float*)d_in[2];
    const float* qk_b     = (const float*)d_in[3];
    const float* v_fact   = (const float*)d_in[4];
    const float* out_fact = (const float*)d_in[5];
    float* out = (float*)d_out;

    const size_t SZ = (size_t)B_ * H_ * T_ * HD_;        // 4M elements
    __hip_bfloat16* qws = (__hip_bfloat16*)d_ws;         // 8 MB
    __hip_bfloat16* kws = qws + SZ;                      // 8 MB
    __hip_bfloat16* vt  = kws + SZ;                      // 8 MB
    float*          yws = (float*)(vt + SZ);             // 16 MB
    __hip_bfloat16* Xb  = (__hip_bfloat16*)(yws + SZ);   // 8 MB
    __hip_bfloat16* Wb  = Xb + SZ;                       // 4 MB

    cast_bf16<<<dim3(2048), 256, 0, stream>>>(x_norm, Xb, 4 * 1024 * 1024 / 8);
    cast_bf16<<<dim3(1024), 256, 0, stream>>>(qk_w, Wb, 2 * 1024 * 1024 / 8);

    qk_gemm_mfma<<<dim3(2048 / 128, 4096 / 128), 256, 0, stream>>>(Xb, Wb, qk_b, qws, kws);
    head_mix_v<<<dim3(B_ * T_ / 2), 256, 0, stream>>>(xt, v_fact, vt);
    attn_mfma<<<dim3(4096), 64, 0, stream>>>(qws, kws, vt, yws);
    head_mix_out<<<dim3(B_ * T_), 256, 0, stream>>>(yws, out_fact, out);
}